// Round 5
// baseline (171.642 us; speedup 1.0000x reference)
//
#include <hip/hip_runtime.h>
#include <cstdint>
#include <cstddef>

#define THETA 1.2f
#define XI 0.3f
#define BDIM 8192
#define DDIM 512
#define NWORK 2080         // 64*65/2 working upper-tri tiles

typedef float f32x4 __attribute__((ext_vector_type(4)));
typedef int i32x8 __attribute__((ext_vector_type(8)));

// Kernel 1: per-row L2 normalize fp32 -> fp8 e4m3 (OCP, HW cvt), sq[row]=||n||^2, zero counter.
__global__ __launch_bounds__(256) void normalize_rows(
    const float* __restrict__ x, unsigned char* __restrict__ nf8,
    float* __restrict__ sq, unsigned int* __restrict__ counter)
{
    if (blockIdx.x == 0 && threadIdx.x == 0) { *counter = 0u; }
    int row = blockIdx.x * 4 + (threadIdx.x >> 6);
    int l = threadIdx.x & 63;
    const float4* xr = (const float4*)(x + (size_t)row * DDIM);
    float4 v0 = xr[2 * l];
    float4 v1 = xr[2 * l + 1];
    float s = v0.x*v0.x + v0.y*v0.y + v0.z*v0.z + v0.w*v0.w
            + v1.x*v1.x + v1.y*v1.y + v1.z*v1.z + v1.w*v1.w;
    #pragma unroll
    for (int m = 1; m < 64; m <<= 1) s += __shfl_xor(s, m);
    float rn = rsqrtf(s);
    int pkL = __builtin_amdgcn_cvt_pk_fp8_f32(v0.x * rn, v0.y * rn, 0, false);
    pkL     = __builtin_amdgcn_cvt_pk_fp8_f32(v0.z * rn, v0.w * rn, pkL, true);
    int pkH = __builtin_amdgcn_cvt_pk_fp8_f32(v1.x * rn, v1.y * rn, 0, false);
    pkH     = __builtin_amdgcn_cvt_pk_fp8_f32(v1.z * rn, v1.w * rn, pkH, true);
    ((int2*)(nf8 + (size_t)row * DDIM))[l] = make_int2(pkL, pkH);
    if (l == 0) sq[row] = s * rn * rn;
}

// Kernel 2: 1D triangular grid, 128x128 Gram tiles, fp8 mfma_scale 16x16x128 (scales=1.0).
// NO LDS staging, NO barriers in the K-loop: fragments are loaded directly from global
// (L2-resident 4 MB matrix) as dwordx4 pairs; the compiler software-pipelines loads
// against MFMAs freely. Fused hinge reduction + per-block partial + ticket finalize.
__global__ __launch_bounds__(256) void gram_hinge(
    const unsigned char* __restrict__ nf8, const float* __restrict__ sq,
    const int* __restrict__ y, double* __restrict__ part,
    unsigned int* __restrict__ counter, float* __restrict__ out)
{
    // decode upper-tri tile (bi, bj), bj >= bi  (verified R1)
    int t = blockIdx.x;
    int bi = (int)((129.0 - sqrt(16641.0 - 8.0 * (double)t)) * 0.5);
    while ((bi + 1) * 64 - ((bi + 1) * bi) / 2 <= t) ++bi;
    while (bi * 64 - (bi * (bi - 1)) / 2 > t) --bi;
    int bj = bi + (t - (bi * 64 - (bi * (bi - 1)) / 2));

    __shared__ float wpart[4];
    __shared__ double dpart[4];
    __shared__ int is_last;

    int tid = threadIdx.x;
    int w = tid >> 6, l = tid & 63;
    int wr = w >> 1, wc = w & 1;     // wave 2x2 -> 64x64 subtile
    int lr = l & 15, q = l >> 4;

    f32x4 accv[4][4] = {};

    // A-operand layout for 16x16x128 f8f6f4 (validated R3): lane (lr,q) holds
    // row = lr, k = q*32 + reg*4 + byte. Two 16-B global loads per fragment.
    const unsigned char* rowA = nf8 + ((size_t)(bi * 128 + wr * 64 + lr)) * DDIM + q * 32;
    const unsigned char* rowB = nf8 + ((size_t)(bj * 128 + wc * 64 + lr)) * DDIM + q * 32;

    #pragma unroll
    for (int it = 0; it < 4; ++it) {
        int k0 = it * 128;
        i32x8 af[4], bfr[4];
        #pragma unroll
        for (int mi = 0; mi < 4; ++mi) {
            const int4* p = (const int4*)(rowA + (size_t)mi * 16 * DDIM + k0);
            int4 a0 = p[0], a1 = p[1];
            af[mi][0] = a0.x; af[mi][1] = a0.y; af[mi][2] = a0.z; af[mi][3] = a0.w;
            af[mi][4] = a1.x; af[mi][5] = a1.y; af[mi][6] = a1.z; af[mi][7] = a1.w;
        }
        #pragma unroll
        for (int ni = 0; ni < 4; ++ni) {
            const int4* p = (const int4*)(rowB + (size_t)ni * 16 * DDIM + k0);
            int4 b0 = p[0], b1 = p[1];
            bfr[ni][0] = b0.x; bfr[ni][1] = b0.y; bfr[ni][2] = b0.z; bfr[ni][3] = b0.w;
            bfr[ni][4] = b1.x; bfr[ni][5] = b1.y; bfr[ni][6] = b1.z; bfr[ni][7] = b1.w;
        }
        #pragma unroll
        for (int mi = 0; mi < 4; ++mi)
            #pragma unroll
            for (int ni = 0; ni < 4; ++ni)
                accv[mi][ni] = __builtin_amdgcn_mfma_scale_f32_16x16x128_f8f6f4(
                    af[mi], bfr[ni], accv[mi][ni],
                    0, 0, 0, 0x7F7F7F7F, 0, 0x7F7F7F7F);
    }

    // Epilogue: C/D layout col=lane&15, row=q*4+reg.
    int jbase = bj * 128 + wc * 64 + lr;
    float sqj[4]; int yj[4];
    #pragma unroll
    for (int ni = 0; ni < 4; ++ni) {
        int gj = jbase + ni * 16;
        sqj[ni] = sq[gj]; yj[ni] = y[gj];
    }
    float local = 0.f;
    #pragma unroll
    for (int mi = 0; mi < 4; ++mi) {
        #pragma unroll
        for (int r = 0; r < 4; ++r) {
            int gi = bi * 128 + wr * 64 + mi * 16 + q * 4 + r;
            float sqi = sq[gi]; int yi = y[gi];
            #pragma unroll
            for (int ni = 0; ni < 4; ++ni) {
                int gj = jbase + ni * 16;
                float G = accv[mi][ni][r];
                float d2 = sqi + sqj[ni] - 2.0f * G;
                float h = fmaxf(THETA - d2, 0.0f);
                float tv = XI + ((yi == yj[ni]) ? h : -h);
                if (gj >= gi) local += tv;
            }
        }
    }
    #pragma unroll
    for (int off = 32; off > 0; off >>= 1) local += __shfl_down(local, off);
    if (l == 0) wpart[w] = local;
    __syncthreads();
    if (tid == 0) {
        double ssum = (double)wpart[0] + (double)wpart[1]
                    + (double)wpart[2] + (double)wpart[3];
        __hip_atomic_store(&part[t], ssum, __ATOMIC_RELEASE, __HIP_MEMORY_SCOPE_AGENT);
        unsigned int ticket = __hip_atomic_fetch_add(
            counter, 1u, __ATOMIC_ACQ_REL, __HIP_MEMORY_SCOPE_AGENT);
        is_last = (ticket == NWORK - 1) ? 1 : 0;
    }
    __syncthreads();
    if (is_last) {
        double s = 0.0;
        for (int i = tid; i < NWORK; i += 256)
            s += __hip_atomic_load(&part[i], __ATOMIC_ACQUIRE, __HIP_MEMORY_SCOPE_AGENT);
        #pragma unroll
        for (int off = 32; off > 0; off >>= 1) s += __shfl_down(s, off);
        if (l == 0) dpart[w] = s;
        __syncthreads();
        if (tid == 0) {
            const double m = 1.0 / ((double)BDIM * (double)BDIM - (double)BDIM);
            out[0] = (float)((dpart[0] + dpart[1] + dpart[2] + dpart[3]) * m);
        }
    }
}

extern "C" void kernel_launch(void* const* d_in, const int* in_sizes, int n_in,
                              void* d_out, int out_size, void* d_ws, size_t ws_size,
                              hipStream_t stream) {
    const float* x = (const float*)d_in[0];
    const int* y = (const int*)d_in[1];
    float* out = (float*)d_out;

    unsigned char* nf8 = (unsigned char*)d_ws;                          // 4 MB fp8
    char* p = (char*)d_ws + (size_t)BDIM * DDIM;
    float* sq = (float*)p;                                              // 32 KB
    unsigned int* counter = (unsigned int*)(p + (size_t)BDIM * 4);
    double* part = (double*)(p + (size_t)BDIM * 4 + 64);                // 2080 doubles

    normalize_rows<<<BDIM / 4, 256, 0, stream>>>(x, nf8, sq, counter);
    gram_hinge<<<NWORK, 256, 0, stream>>>(nf8, sq, y, part, counter, out);
}

// Round 6
// 140.430 us; speedup vs baseline: 1.2223x; 1.2223x over previous
//
#include <hip/hip_runtime.h>
#include <cstdint>
#include <cstddef>

#define THETA 1.2f
#define XI 0.3f
#define BDIM 8192
#define DDIM 512
#define NSTRIP 544         // sum over bi of (16 - bi/4) j-strip blocks

typedef float f32x4 __attribute__((ext_vector_type(4)));
typedef int i32x8 __attribute__((ext_vector_type(8)));

// Kernel 1: per-row L2 normalize fp32 -> fp8 e4m3 (OCP, HW cvt), sq[row]=||n||^2, zero counter.
__global__ __launch_bounds__(256) void normalize_rows(
    const float* __restrict__ x, unsigned char* __restrict__ nf8,
    float* __restrict__ sq, unsigned int* __restrict__ counter)
{
    if (blockIdx.x == 0 && threadIdx.x == 0) { *counter = 0u; }
    int row = blockIdx.x * 4 + (threadIdx.x >> 6);
    int l = threadIdx.x & 63;
    const float4* xr = (const float4*)(x + (size_t)row * DDIM);
    float4 v0 = xr[2 * l];
    float4 v1 = xr[2 * l + 1];
    float s = v0.x*v0.x + v0.y*v0.y + v0.z*v0.z + v0.w*v0.w
            + v1.x*v1.x + v1.y*v1.y + v1.z*v1.z + v1.w*v1.w;
    #pragma unroll
    for (int m = 1; m < 64; m <<= 1) s += __shfl_xor(s, m);
    float rn = rsqrtf(s);
    int pkL = __builtin_amdgcn_cvt_pk_fp8_f32(v0.x * rn, v0.y * rn, 0, false);
    pkL     = __builtin_amdgcn_cvt_pk_fp8_f32(v0.z * rn, v0.w * rn, pkL, true);
    int pkH = __builtin_amdgcn_cvt_pk_fp8_f32(v1.x * rn, v1.y * rn, 0, false);
    pkH     = __builtin_amdgcn_cvt_pk_fp8_f32(v1.z * rn, v1.w * rn, pkH, true);
    ((int2*)(nf8 + (size_t)row * DDIM))[l] = make_int2(pkL, pkH);
    if (l == 0) sq[row] = s * rn * rn;
}

// Kernel 2: j-strip blocks. Each block: stage A-panel (128 x 512 fp8 = 64 KB) to LDS ONCE
// (contiguous 1-KB DMA, one barrier), then 4 j-tiles x 4 K-iters of barrier-free
// ds_read(A) + global(B) + mfma_scale_f32_16x16x128_f8f6f4. Fused hinge + ticket finalize.
__global__ __launch_bounds__(256) void gram_hinge(
    const unsigned char* __restrict__ nf8, const float* __restrict__ sq,
    const int* __restrict__ y, double* __restrict__ part,
    unsigned int* __restrict__ counter, float* __restrict__ out)
{
    // decode strip: bi in 0..63, jg in bi/4..15
    int t = blockIdx.x;
    int bi = 0, jg = 0;
    {
        int cum = 0;
        for (int b = 0; b < 64; ++b) {
            int c = 16 - (b >> 2);
            if (t < cum + c) { bi = b; jg = (b >> 2) + (t - cum); break; }
            cum += c;
        }
    }

    __shared__ unsigned char As[128 * 512];   // 64 KB A-panel, granule-swizzled rows
    __shared__ float wpart[4];
    __shared__ double dpart[4];
    __shared__ int is_last;

    int tid = threadIdx.x;
    int w = tid >> 6, l = tid & 63;
    int wr = w >> 1, wc = w & 1;     // wave 2x2 -> 64x64 per 128x128 tile
    int lr = l & 15, q = l >> 4;

    // ---- stage A-panel: 16 DMA instrs/wave, each 2 full rows (1 KB contiguous) ----
    // lane l: local row = base + (l>>5), granule (l&31); fetch global granule (l&31)^(row&7)
    const unsigned char* gA = nf8 + (size_t)bi * 128 * DDIM;
    {
        int rl = (l >> 5);           // 0/1 within row pair
        int gl = l & 31;             // LDS granule
        #pragma unroll
        for (int i = 0; i < 16; ++i) {
            int rbase = w * 32 + i * 2;
            int r = rbase + rl;
            int gg = gl ^ (r & 7);   // in-row 16-B granule swizzle (coalescing-safe)
            __builtin_amdgcn_global_load_lds(
                (const __attribute__((address_space(1))) void*)(gA + (size_t)r * DDIM + gg * 16),
                (__attribute__((address_space(3))) void*)(As + rbase * 512), 16, 0, 0);
        }
    }
    __syncthreads();   // single drain+barrier for the whole block

    float local = 0.f;

    for (int jt = 0; jt < 4; ++jt) {
        int bj = jg * 4 + jt;
        if (bj < bi) continue;       // wave-uniform skip of below-diagonal tiles

        f32x4 accv[4][4] = {};
        const unsigned char* rowB =
            nf8 + ((size_t)(bj * 128 + wc * 64 + lr)) * DDIM + q * 32;

        #pragma unroll
        for (int it = 0; it < 4; ++it) {
            int k0 = it * 128;
            i32x8 af[4], bfr[4];
            // A from LDS: lane(lr,q) row=wr*64+mi*16+lr, granules (it*8+q*2)|{0,1} ^ (row&7)
            #pragma unroll
            for (int mi = 0; mi < 4; ++mi) {
                int r = wr * 64 + mi * 16 + lr;
                int gb = it * 8 + q * 2;
                int sw = r & 7;
                int4 a0 = *(const int4*)(As + r * 512 + ((gb ^ sw) << 4));
                int4 a1 = *(const int4*)(As + r * 512 + (((gb | 1) ^ sw) << 4));
                af[mi][0] = a0.x; af[mi][1] = a0.y; af[mi][2] = a0.z; af[mi][3] = a0.w;
                af[mi][4] = a1.x; af[mi][5] = a1.y; af[mi][6] = a1.z; af[mi][7] = a1.w;
            }
            // B direct from global (L2-hot), 32 B contiguous per lane
            #pragma unroll
            for (int ni = 0; ni < 4; ++ni) {
                const int4* p = (const int4*)(rowB + (size_t)ni * 16 * DDIM + k0);
                int4 b0 = p[0], b1 = p[1];
                bfr[ni][0] = b0.x; bfr[ni][1] = b0.y; bfr[ni][2] = b0.z; bfr[ni][3] = b0.w;
                bfr[ni][4] = b1.x; bfr[ni][5] = b1.y; bfr[ni][6] = b1.z; bfr[ni][7] = b1.w;
            }
            #pragma unroll
            for (int mi = 0; mi < 4; ++mi)
                #pragma unroll
                for (int ni = 0; ni < 4; ++ni)
                    accv[mi][ni] = __builtin_amdgcn_mfma_scale_f32_16x16x128_f8f6f4(
                        af[mi], bfr[ni], accv[mi][ni],
                        0, 0, 0, 0x7F7F7F7F, 0, 0x7F7F7F7F);
        }

        // Epilogue for this tile: C/D layout col=lane&15, row=q*4+reg.
        int jbase = bj * 128 + wc * 64 + lr;
        float sqj[4]; int yj[4];
        #pragma unroll
        for (int ni = 0; ni < 4; ++ni) {
            int gj = jbase + ni * 16;
            sqj[ni] = sq[gj]; yj[ni] = y[gj];
        }
        #pragma unroll
        for (int mi = 0; mi < 4; ++mi) {
            #pragma unroll
            for (int r = 0; r < 4; ++r) {
                int gi = bi * 128 + wr * 64 + mi * 16 + q * 4 + r;
                float sqi = sq[gi]; int yi = y[gi];
                #pragma unroll
                for (int ni = 0; ni < 4; ++ni) {
                    int gj = jbase + ni * 16;
                    float G = accv[mi][ni][r];
                    float d2 = sqi + sqj[ni] - 2.0f * G;
                    float h = fmaxf(THETA - d2, 0.0f);
                    float tv = XI + ((yi == yj[ni]) ? h : -h);
                    if (gj >= gi) local += tv;
                }
            }
        }
    }

    #pragma unroll
    for (int off = 32; off > 0; off >>= 1) local += __shfl_down(local, off);
    if (l == 0) wpart[w] = local;
    __syncthreads();
    if (tid == 0) {
        double ssum = (double)wpart[0] + (double)wpart[1]
                    + (double)wpart[2] + (double)wpart[3];
        __hip_atomic_store(&part[t], ssum, __ATOMIC_RELEASE, __HIP_MEMORY_SCOPE_AGENT);
        unsigned int ticket = __hip_atomic_fetch_add(
            counter, 1u, __ATOMIC_ACQ_REL, __HIP_MEMORY_SCOPE_AGENT);
        is_last = (ticket == NSTRIP - 1) ? 1 : 0;
    }
    __syncthreads();
    if (is_last) {
        double s = 0.0;
        for (int i = tid; i < NSTRIP; i += 256)
            s += __hip_atomic_load(&part[i], __ATOMIC_ACQUIRE, __HIP_MEMORY_SCOPE_AGENT);
        #pragma unroll
        for (int off = 32; off > 0; off >>= 1) s += __shfl_down(s, off);
        if (l == 0) dpart[w] = s;
        __syncthreads();
        if (tid == 0) {
            const double m = 1.0 / ((double)BDIM * (double)BDIM - (double)BDIM);
            out[0] = (float)((dpart[0] + dpart[1] + dpart[2] + dpart[3]) * m);
        }
    }
}

extern "C" void kernel_launch(void* const* d_in, const int* in_sizes, int n_in,
                              void* d_out, int out_size, void* d_ws, size_t ws_size,
                              hipStream_t stream) {
    const float* x = (const float*)d_in[0];
    const int* y = (const int*)d_in[1];
    float* out = (float*)d_out;

    unsigned char* nf8 = (unsigned char*)d_ws;                          // 4 MB fp8
    char* p = (char*)d_ws + (size_t)BDIM * DDIM;
    float* sq = (float*)p;                                              // 32 KB
    unsigned int* counter = (unsigned int*)(p + (size_t)BDIM * 4);
    double* part = (double*)(p + (size_t)BDIM * 4 + 64);                // NSTRIP doubles

    normalize_rows<<<BDIM / 4, 256, 0, stream>>>(x, nf8, sq, counter);
    gram_hinge<<<NSTRIP, 256, 0, stream>>>(nf8, sq, y, part, counter, out);
}